// Round 3
// baseline (1776.008 us; speedup 1.0000x reference)
//
#include <hip/hip_runtime.h>

#define NTHREADS 512

typedef __attribute__((ext_vector_type(8))) short s16x8;
typedef __attribute__((ext_vector_type(4))) float f32x4;
typedef __attribute__((ext_vector_type(4))) unsigned int u32x4;

__device__ __forceinline__ unsigned short f2bf(float f) {
  unsigned u = __float_as_uint(f);
  u += 0x7fffu + ((u >> 16) & 1u);
  return (unsigned short)(u >> 16);
}
__device__ __forceinline__ float bf2f(unsigned short s) {
  return __uint_as_float(((unsigned)s) << 16);
}
__device__ __forceinline__ float sigm(float x) {
  return __builtin_amdgcn_rcpf(1.0f + __expf(-x));
}
__device__ __forceinline__ float tanh_fast(float x) {
  return 1.0f - 2.0f * __builtin_amdgcn_rcpf(1.0f + __expf(2.0f * x));
}
__device__ __forceinline__ f32x4 mfma_bf16(u32x4 a, u32x4 b, f32x4 c) {
  union { u32x4 u; s16x8 s; } ua, ub;
  ua.u = a; ub.u = b;
  return __builtin_amdgcn_mfma_f32_16x16x32_bf16(ua.s, ub.s, c, 0, 0, 0);
}

// ---------------- weight pre-pack (unchanged, verified) ----------------
// W0p: layer0 combined [n=4H][K=416] (k<160: W_ih0, else W_hh0), bf16,
//      layout [nblk][kblk][16 n][8 k]; W1p: layer1 K=512, KB=64.
// b0/b1: b_ih + b_hh pre-summed, f32.
__global__ void pack_weights(const float* __restrict__ Wih0, const float* __restrict__ Whh0,
                             const float* __restrict__ bih0, const float* __restrict__ bhh0,
                             const float* __restrict__ Wih1, const float* __restrict__ Whh1,
                             const float* __restrict__ bih1, const float* __restrict__ bhh1,
                             unsigned short* __restrict__ W0p, unsigned short* __restrict__ W1p,
                             float* __restrict__ b0, float* __restrict__ b1) {
  int e = blockIdx.x * 256 + threadIdx.x;
  const int N0 = 1024 * 416;
  const int N1 = 1024 * 512;
  if (e < N0) {
    int kk = e & 7, t1 = e >> 3;
    int n = t1 & 15, t2 = t1 >> 4;
    int kb = t2 % 52, nb = t2 / 52;
    int gn = nb * 16 + n, k = kb * 8 + kk;
    float v = (k < 160) ? Wih0[gn * 160 + k] : Whh0[gn * 256 + (k - 160)];
    W0p[e] = f2bf(v);
  } else if (e < N0 + N1) {
    int e2 = e - N0;
    int kk = e2 & 7, t1 = e2 >> 3;
    int n = t1 & 15, t2 = t1 >> 4;
    int kb = t2 & 63, nb = t2 >> 6;
    int gn = nb * 16 + n, k = kb * 8 + kk;
    float v = (k < 256) ? Wih1[gn * 256 + k] : Whh1[gn * 256 + (k - 256)];
    W1p[e2] = f2bf(v);
  } else if (e < N0 + N1 + 1024) {
    int n = e - (N0 + N1);
    b0[n] = bih0[n] + bhh0[n];
  } else if (e < N0 + N1 + 2048) {
    int n = e - (N0 + N1 + 1024);
    b1[n] = bih1[n] + bhh1[n];
  }
}

// ---------------- fused 2-layer LSTM + FC ----------------
// 256 blocks x 512 threads; block owns 64 batch rows for all 10 steps.
// LDS 150 KB (1 blk/CU, 2 waves/SIMD): x-tile + DOUBLE-BUFFERED h1/h2 in
// bf16 A-layout [kblk][row][8k]. Dbuf removes all WAR hazards -> 3 barriers
// per step, no h-holding registers.
// Register budget (256 total @ 2 waves/EU): acc 64 (AGPR) + c-state 64 +
// av dbuf 32 + bv dbuf 32 + bias 16 + misc ~30 ~= 238. Round-1/2 spilled
// (939 MB scratch writes) because explicit staging was 80+ VGPRs + hpk.
__global__ __launch_bounds__(NTHREADS, 2)
void lstm_fused(const float* __restrict__ x,
                const unsigned short* __restrict__ W0p,
                const unsigned short* __restrict__ W1p,
                const float* __restrict__ b0,
                const float* __restrict__ b1,
                const float* __restrict__ Wfc,
                const float* __restrict__ bfc,
                float* __restrict__ out) {
  __shared__ unsigned int lds_x[20 * 64 * 4];   // 20480 B
  __shared__ unsigned int lds_h1[16384];        // 65536 B = 2 bufs x [32 kblk][64 row][8k]
  __shared__ unsigned int lds_h2[16384];        // 65536 B
  __shared__ float lds_red[512];                // 2048 B        total 153600 B

  const int tid = threadIdx.x;
  const int wave = tid >> 6;
  const int lane = tid & 63;
  const int l15 = lane & 15;
  const int quad = lane >> 4;
  const long rowg0 = (long)blockIdx.x * 64;

  for (int i = tid; i < 16384; i += NTHREADS) { lds_h1[i] = 0u; lds_h2[i] = 0u; }

  // persistent per-thread biases (t-invariant): 16 regs
  float bs0[2][4], bs1[2][4];
#pragma unroll
  for (int jt = 0; jt < 2; jt++)
#pragma unroll
    for (int g = 0; g < 4; g++) {
      bs0[jt][g] = b0[g * 256 + wave * 32 + jt * 16 + l15];
      bs1[jt][g] = b1[g * 256 + wave * 32 + jt * 16 + l15];
    }

  f32x4 c0[2][4], c2[2][4];
#pragma unroll
  for (int jt = 0; jt < 2; jt++)
#pragma unroll
    for (int rt = 0; rt < 4; rt++) {
      c0[jt][rt] = (f32x4){0.f, 0.f, 0.f, 0.f};
      c2[jt][rt] = (f32x4){0.f, 0.f, 0.f, 0.f};
    }
  float fc_acc = 0.0f;

  const u32x4* lxs = (const u32x4*)lds_x;
  const u32x4* lh1 = (const u32x4*)lds_h1;
  const u32x4* lh2 = (const u32x4*)lds_h2;
  unsigned short* lh1s = (unsigned short*)lds_h1;
  unsigned short* lh2s = (unsigned short*)lds_h2;
  const u32x4* w0q = (const u32x4*)W0p;
  const u32x4* w1q = (const u32x4*)W1p;

  for (int t = 0; t < 10; t++) {
    const int rd = t & 1;        // prev-h buffer
    const int wr = rd ^ 1;       // new-h buffer

    // ---- stage x_t -> lds_x (bf16 A-layout) ----
#pragma unroll
    for (int s = 0; s < 5; s++) {
      int p = tid + s * NTHREADS;          // 2560 f32x4 = 64 rows x 40 quads
      int row = p / 40;
      int kq = p - row * 40;
      const f32x4 v = __builtin_nontemporal_load(
          (const f32x4*)(x + (rowg0 + row) * 1600 + t * 160 + kq * 4));
      unsigned lo = (unsigned)f2bf(v[0]) | ((unsigned)f2bf(v[1]) << 16);
      unsigned hi = (unsigned)f2bf(v[2]) | ((unsigned)f2bf(v[3]) << 16);
      int base = (kq >> 1) * 256 + row * 4 + (kq & 1) * 2;
      lds_x[base] = lo;
      lds_x[base + 1] = hi;
    }
    __syncthreads();  // B1: x staged; h1[rd] stable from prev step

    // ======== layer 0: K=416 ([x_t | h1_prev]) ========
#pragma unroll
    for (int jt = 0; jt < 2; jt++) {
      const int nbb = wave * 2 + jt;
      f32x4 acc[4][4];
#pragma unroll
      for (int g = 0; g < 4; g++)
#pragma unroll
        for (int rt = 0; rt < 4; rt++) acc[g][rt] = (f32x4){0.f, 0.f, 0.f, 0.f};

      u32x4 av[2][4], bv[2][4];
#pragma unroll
      for (int g = 0; g < 4; g++)
        bv[0][g] = w0q[((g * 16 + nbb) * 52 + quad) * 16 + l15];
#pragma unroll
      for (int rt = 0; rt < 4; rt++) av[0][rt] = lxs[quad * 64 + rt * 16 + l15];

#pragma unroll
      for (int ki = 0; ki < 13; ki++) {
        const int cur = ki & 1, nxt = cur ^ 1;
        if (ki < 12) {
          const int k0n = (ki + 1) * 32;
#pragma unroll
          for (int g = 0; g < 4; g++)
            bv[nxt][g] = w0q[((g * 16 + nbb) * 52 + (ki + 1) * 4 + quad) * 16 + l15];
          const u32x4* ab = (k0n < 160)
              ? (lxs + ((k0n >> 3) + quad) * 64)
              : (lh1 + rd * 2048 + (((k0n - 160) >> 3) + quad) * 64);
#pragma unroll
          for (int rt = 0; rt < 4; rt++) av[nxt][rt] = ab[rt * 16 + l15];
        }
#pragma unroll
        for (int g = 0; g < 4; g++)
#pragma unroll
          for (int rt = 0; rt < 4; rt++)
            acc[g][rt] = mfma_bf16(av[cur][rt], bv[cur][g], acc[g][rt]);
      }
      // epilogue: gates -> c0, h1 -> lds_h1[wr] (dbuf: no WAR, write now)
#pragma unroll
      for (int rt = 0; rt < 4; rt++)
#pragma unroll
        for (int r = 0; r < 4; r++) {
          float iv = sigm(acc[0][rt][r] + bs0[jt][0]);
          float fv = sigm(acc[1][rt][r] + bs0[jt][1]);
          float gv = tanh_fast(acc[2][rt][r] + bs0[jt][2]);
          float ov = sigm(acc[3][rt][r] + bs0[jt][3]);
          float cn = fv * c0[jt][rt][r] + iv * gv;
          c0[jt][rt][r] = cn;
          int row = rt * 16 + quad * 4 + r;
          int col = wave * 32 + jt * 16 + l15;
          lh1s[wr * 16384 + ((col >> 3) * 64 + row) * 8 + (col & 7)] =
              f2bf(ov * tanh_fast(cn));
        }
    }
    __syncthreads();  // B2: h1[wr] complete

    // ======== layer 1: K=512 ([h1_new | h2_prev]) ========
#pragma unroll
    for (int jt = 0; jt < 2; jt++) {
      const int nbb = wave * 2 + jt;
      f32x4 acc[4][4];
#pragma unroll
      for (int g = 0; g < 4; g++)
#pragma unroll
        for (int rt = 0; rt < 4; rt++) acc[g][rt] = (f32x4){0.f, 0.f, 0.f, 0.f};

      u32x4 av[2][4], bv[2][4];
#pragma unroll
      for (int g = 0; g < 4; g++)
        bv[0][g] = w1q[((g * 16 + nbb) * 64 + quad) * 16 + l15];
#pragma unroll
      for (int rt = 0; rt < 4; rt++)
        av[0][rt] = lh1[wr * 2048 + quad * 64 + rt * 16 + l15];

#pragma unroll
      for (int ki = 0; ki < 16; ki++) {
        const int cur = ki & 1, nxt = cur ^ 1;
        if (ki < 15) {
          const int k0n = (ki + 1) * 32;
#pragma unroll
          for (int g = 0; g < 4; g++)
            bv[nxt][g] = w1q[((g * 16 + nbb) * 64 + (ki + 1) * 4 + quad) * 16 + l15];
          const u32x4* ab = (k0n < 256)
              ? (lh1 + wr * 2048 + ((k0n >> 3) + quad) * 64)
              : (lh2 + rd * 2048 + (((k0n - 256) >> 3) + quad) * 64);
#pragma unroll
          for (int rt = 0; rt < 4; rt++) av[nxt][rt] = ab[rt * 16 + l15];
        }
#pragma unroll
        for (int g = 0; g < 4; g++)
#pragma unroll
          for (int rt = 0; rt < 4; rt++)
            acc[g][rt] = mfma_bf16(av[cur][rt], bv[cur][g], acc[g][rt]);
      }
#pragma unroll
      for (int rt = 0; rt < 4; rt++)
#pragma unroll
        for (int r = 0; r < 4; r++) {
          float iv = sigm(acc[0][rt][r] + bs1[jt][0]);
          float fv = sigm(acc[1][rt][r] + bs1[jt][1]);
          float gv = tanh_fast(acc[2][rt][r] + bs1[jt][2]);
          float ov = sigm(acc[3][rt][r] + bs1[jt][3]);
          float cn = fv * c2[jt][rt][r] + iv * gv;
          c2[jt][rt][r] = cn;
          int row = rt * 16 + quad * 4 + r;
          int col = wave * 32 + jt * 16 + l15;
          lh2s[wr * 16384 + ((col >> 3) * 64 + row) * 8 + (col & 7)] =
              f2bf(ov * tanh_fast(cn));
        }
    }
    __syncthreads();  // B3: h2[wr] complete

    // ---- FC partial: logit += W_fc[t*256 + j] * h2_new[row][j] ----
    {
      int row = tid >> 3;
      int jq = (tid & 7) * 32;
      float s = 0.f;
#pragma unroll
      for (int kb = 0; kb < 4; kb++) {
        u32x4 hv = lh2[wr * 2048 + ((jq >> 3) + kb) * 64 + row];
        const f32x4 wA = *(const f32x4*)(Wfc + t * 256 + jq + kb * 8);
        const f32x4 wB = *(const f32x4*)(Wfc + t * 256 + jq + kb * 8 + 4);
#pragma unroll
        for (int e = 0; e < 2; e++) {
          unsigned u = hv[e];
          s += bf2f((unsigned short)(u & 0xffffu)) * wA[2 * e];
          s += bf2f((unsigned short)(u >> 16)) * wA[2 * e + 1];
        }
#pragma unroll
        for (int e = 0; e < 2; e++) {
          unsigned u = hv[2 + e];
          s += bf2f((unsigned short)(u & 0xffffu)) * wB[2 * e];
          s += bf2f((unsigned short)(u >> 16)) * wB[2 * e + 1];
        }
      }
      fc_acc += s;
    }
    // no barrier: next staging touches lds_x only (last read before B2);
    // dbuf guarantees no h region is rewritten while readable.
  }

  lds_red[tid] = fc_acc;  // [row(64)][slot(8)]
  __syncthreads();
  if (tid < 64) {
    float s = 0.f;
#pragma unroll
    for (int e = 0; e < 8; e++) s += lds_red[tid * 8 + e];
    out[rowg0 + tid] = sigm(s + bfc[0]);
  }
}

extern "C" void kernel_launch(void* const* d_in, const int* in_sizes, int n_in,
                              void* d_out, int out_size, void* d_ws, size_t ws_size,
                              hipStream_t stream) {
  const float* x    = (const float*)d_in[0];
  const float* Wih0 = (const float*)d_in[1];
  const float* Whh0 = (const float*)d_in[2];
  const float* bih0 = (const float*)d_in[3];
  const float* bhh0 = (const float*)d_in[4];
  const float* Wih1 = (const float*)d_in[5];
  const float* Whh1 = (const float*)d_in[6];
  const float* bih1 = (const float*)d_in[7];
  const float* bhh1 = (const float*)d_in[8];
  const float* Wfc  = (const float*)d_in[9];
  const float* bfc  = (const float*)d_in[10];
  float* out = (float*)d_out;

  unsigned short* W0p = (unsigned short*)d_ws;         // 1024*416 bf16
  unsigned short* W1p = W0p + 1024 * 416;              // 1024*512 bf16
  float* b0 = (float*)(W1p + 1024 * 512);              // 1024 f32
  float* b1 = b0 + 1024;                               // 1024 f32

  const int total = 1024 * 416 + 1024 * 512 + 2048;
  pack_weights<<<(total + 255) / 256, 256, 0, stream>>>(
      Wih0, Whh0, bih0, bhh0, Wih1, Whh1, bih1, bhh1, W0p, W1p, b0, b1);
  lstm_fused<<<256, NTHREADS, 0, stream>>>(x, W0p, W1p, b0, b1, Wfc, bfc, out);
}

// Round 4
// 1768.098 us; speedup vs baseline: 1.0045x; 1.0045x over previous
//
#include <hip/hip_runtime.h>

#define NTHREADS 512

typedef __attribute__((ext_vector_type(8))) short s16x8;
typedef __attribute__((ext_vector_type(4))) float f32x4;
typedef __attribute__((ext_vector_type(4))) unsigned int u32x4;

__device__ __forceinline__ unsigned short f2bf(float f) {
  unsigned u = __float_as_uint(f);
  u += 0x7fffu + ((u >> 16) & 1u);
  return (unsigned short)(u >> 16);
}
__device__ __forceinline__ float bf2f(unsigned short s) {
  return __uint_as_float(((unsigned)s) << 16);
}
__device__ __forceinline__ float sigm(float x) {
  return __builtin_amdgcn_rcpf(1.0f + __expf(-x));
}
__device__ __forceinline__ float tanh_fast(float x) {
  return 1.0f - 2.0f * __builtin_amdgcn_rcpf(1.0f + __expf(2.0f * x));
}
__device__ __forceinline__ f32x4 mfma_bf16(u32x4 a, u32x4 b, f32x4 c) {
  union { u32x4 u; s16x8 s; } ua, ub;
  ua.u = a; ub.u = b;
  return __builtin_amdgcn_mfma_f32_16x16x32_bf16(ua.s, ub.s, c, 0, 0, 0);
}

// ---------------- weight pre-pack (unchanged, verified) ----------------
// W0p: layer0 combined [n=4H][K=416] (k<160: W_ih0, else W_hh0), bf16,
//      layout [nblk][kblk][16 n][8 k]; W1p: layer1 K=512, KB=64.
// b0/b1: b_ih + b_hh pre-summed, f32.
__global__ void pack_weights(const float* __restrict__ Wih0, const float* __restrict__ Whh0,
                             const float* __restrict__ bih0, const float* __restrict__ bhh0,
                             const float* __restrict__ Wih1, const float* __restrict__ Whh1,
                             const float* __restrict__ bih1, const float* __restrict__ bhh1,
                             unsigned short* __restrict__ W0p, unsigned short* __restrict__ W1p,
                             float* __restrict__ b0, float* __restrict__ b1) {
  int e = blockIdx.x * 256 + threadIdx.x;
  const int N0 = 1024 * 416;
  const int N1 = 1024 * 512;
  if (e < N0) {
    int kk = e & 7, t1 = e >> 3;
    int n = t1 & 15, t2 = t1 >> 4;
    int kb = t2 % 52, nb = t2 / 52;
    int gn = nb * 16 + n, k = kb * 8 + kk;
    float v = (k < 160) ? Wih0[gn * 160 + k] : Whh0[gn * 256 + (k - 160)];
    W0p[e] = f2bf(v);
  } else if (e < N0 + N1) {
    int e2 = e - N0;
    int kk = e2 & 7, t1 = e2 >> 3;
    int n = t1 & 15, t2 = t1 >> 4;
    int kb = t2 & 63, nb = t2 >> 6;
    int gn = nb * 16 + n, k = kb * 8 + kk;
    float v = (k < 256) ? Wih1[gn * 256 + k] : Whh1[gn * 256 + (k - 256)];
    W1p[e2] = f2bf(v);
  } else if (e < N0 + N1 + 1024) {
    int n = e - (N0 + N1);
    b0[n] = bih0[n] + bhh0[n];
  } else if (e < N0 + N1 + 2048) {
    int n = e - (N0 + N1 + 1024);
    b1[n] = bih1[n] + bhh1[n];
  }
}

// ---------------- fused 2-layer LSTM + FC ----------------
// 256 blocks x 512 threads; block owns 64 batch rows for all 10 steps.
// LDS 150 KB (1 blk/CU, 2 waves/SIMD): x-tile + DOUBLE-BUFFERED h1/h2 in
// bf16 A-layout [kblk][row][8k]; 3 barriers/step.
// OCCUPANCY PIN: rounds 1-3 all came back VGPR_Count=128 + ~0.5-1 GB of
// scratch spill regardless of __launch_bounds__ 2nd arg — the RA budgeted
// 4 waves/EU. amdgpu_waves_per_eu(2,2) pins the budget to 512/2 = 256
// unified regs/wave; live set is ~225 (acc 64 AGPR + c 64 + av/bv dbuf 64
// + bias 16 + temps) so no spill is needed at 256.
__global__ __attribute__((amdgpu_flat_work_group_size(NTHREADS, NTHREADS),
                          amdgpu_waves_per_eu(2, 2)))
void lstm_fused(const float* __restrict__ x,
                const unsigned short* __restrict__ W0p,
                const unsigned short* __restrict__ W1p,
                const float* __restrict__ b0,
                const float* __restrict__ b1,
                const float* __restrict__ Wfc,
                const float* __restrict__ bfc,
                float* __restrict__ out) {
  __shared__ unsigned int lds_x[20 * 64 * 4];   // 20480 B
  __shared__ unsigned int lds_h1[16384];        // 65536 B = 2 bufs x [32 kblk][64 row][8k]
  __shared__ unsigned int lds_h2[16384];        // 65536 B
  __shared__ float lds_red[512];                // 2048 B        total 153600 B

  const int tid = threadIdx.x;
  const int wave = tid >> 6;
  const int lane = tid & 63;
  const int l15 = lane & 15;
  const int quad = lane >> 4;
  const long rowg0 = (long)blockIdx.x * 64;

  for (int i = tid; i < 16384; i += NTHREADS) { lds_h1[i] = 0u; lds_h2[i] = 0u; }

  // persistent per-thread biases (t-invariant): 16 regs
  float bs0[2][4], bs1[2][4];
#pragma unroll
  for (int jt = 0; jt < 2; jt++)
#pragma unroll
    for (int g = 0; g < 4; g++) {
      bs0[jt][g] = b0[g * 256 + wave * 32 + jt * 16 + l15];
      bs1[jt][g] = b1[g * 256 + wave * 32 + jt * 16 + l15];
    }

  f32x4 c0[2][4], c2[2][4];
#pragma unroll
  for (int jt = 0; jt < 2; jt++)
#pragma unroll
    for (int rt = 0; rt < 4; rt++) {
      c0[jt][rt] = (f32x4){0.f, 0.f, 0.f, 0.f};
      c2[jt][rt] = (f32x4){0.f, 0.f, 0.f, 0.f};
    }
  float fc_acc = 0.0f;

  const u32x4* lxs = (const u32x4*)lds_x;
  const u32x4* lh1 = (const u32x4*)lds_h1;
  const u32x4* lh2 = (const u32x4*)lds_h2;
  unsigned short* lh1s = (unsigned short*)lds_h1;
  unsigned short* lh2s = (unsigned short*)lds_h2;
  const u32x4* w0q = (const u32x4*)W0p;
  const u32x4* w1q = (const u32x4*)W1p;

  for (int t = 0; t < 10; t++) {
    const int rd = t & 1;        // prev-h buffer
    const int wr = rd ^ 1;       // new-h buffer

    // ---- stage x_t -> lds_x (bf16 A-layout) ----
#pragma unroll
    for (int s = 0; s < 5; s++) {
      int p = tid + s * NTHREADS;          // 2560 f32x4 = 64 rows x 40 quads
      int row = p / 40;
      int kq = p - row * 40;
      const f32x4 v = __builtin_nontemporal_load(
          (const f32x4*)(x + (rowg0 + row) * 1600 + t * 160 + kq * 4));
      unsigned lo = (unsigned)f2bf(v[0]) | ((unsigned)f2bf(v[1]) << 16);
      unsigned hi = (unsigned)f2bf(v[2]) | ((unsigned)f2bf(v[3]) << 16);
      int base = (kq >> 1) * 256 + row * 4 + (kq & 1) * 2;
      lds_x[base] = lo;
      lds_x[base + 1] = hi;
    }
    __syncthreads();  // B1: x staged; h1[rd] stable from prev step

    // ======== layer 0: K=416 ([x_t | h1_prev]) ========
#pragma unroll
    for (int jt = 0; jt < 2; jt++) {
      const int nbb = wave * 2 + jt;
      f32x4 acc[4][4];
#pragma unroll
      for (int g = 0; g < 4; g++)
#pragma unroll
        for (int rt = 0; rt < 4; rt++) acc[g][rt] = (f32x4){0.f, 0.f, 0.f, 0.f};

      u32x4 av[2][4], bv[2][4];
#pragma unroll
      for (int g = 0; g < 4; g++)
        bv[0][g] = w0q[((g * 16 + nbb) * 52 + quad) * 16 + l15];
#pragma unroll
      for (int rt = 0; rt < 4; rt++) av[0][rt] = lxs[quad * 64 + rt * 16 + l15];

#pragma unroll
      for (int ki = 0; ki < 13; ki++) {
        const int cur = ki & 1, nxt = cur ^ 1;
        if (ki < 12) {
          const int k0n = (ki + 1) * 32;
#pragma unroll
          for (int g = 0; g < 4; g++)
            bv[nxt][g] = w0q[((g * 16 + nbb) * 52 + (ki + 1) * 4 + quad) * 16 + l15];
          const u32x4* ab = (k0n < 160)
              ? (lxs + ((k0n >> 3) + quad) * 64)
              : (lh1 + rd * 2048 + (((k0n - 160) >> 3) + quad) * 64);
#pragma unroll
          for (int rt = 0; rt < 4; rt++) av[nxt][rt] = ab[rt * 16 + l15];
        }
#pragma unroll
        for (int g = 0; g < 4; g++)
#pragma unroll
          for (int rt = 0; rt < 4; rt++)
            acc[g][rt] = mfma_bf16(av[cur][rt], bv[cur][g], acc[g][rt]);
      }
      // epilogue: gates -> c0, h1 -> lds_h1[wr] (dbuf: no WAR, write now)
#pragma unroll
      for (int rt = 0; rt < 4; rt++)
#pragma unroll
        for (int r = 0; r < 4; r++) {
          float iv = sigm(acc[0][rt][r] + bs0[jt][0]);
          float fv = sigm(acc[1][rt][r] + bs0[jt][1]);
          float gv = tanh_fast(acc[2][rt][r] + bs0[jt][2]);
          float ov = sigm(acc[3][rt][r] + bs0[jt][3]);
          float cn = fv * c0[jt][rt][r] + iv * gv;
          c0[jt][rt][r] = cn;
          int row = rt * 16 + quad * 4 + r;
          int col = wave * 32 + jt * 16 + l15;
          lh1s[wr * 16384 + ((col >> 3) * 64 + row) * 8 + (col & 7)] =
              f2bf(ov * tanh_fast(cn));
        }
    }
    __syncthreads();  // B2: h1[wr] complete

    // ======== layer 1: K=512 ([h1_new | h2_prev]) ========
#pragma unroll
    for (int jt = 0; jt < 2; jt++) {
      const int nbb = wave * 2 + jt;
      f32x4 acc[4][4];
#pragma unroll
      for (int g = 0; g < 4; g++)
#pragma unroll
        for (int rt = 0; rt < 4; rt++) acc[g][rt] = (f32x4){0.f, 0.f, 0.f, 0.f};

      u32x4 av[2][4], bv[2][4];
#pragma unroll
      for (int g = 0; g < 4; g++)
        bv[0][g] = w1q[((g * 16 + nbb) * 64 + quad) * 16 + l15];
#pragma unroll
      for (int rt = 0; rt < 4; rt++)
        av[0][rt] = lh1[wr * 2048 + quad * 64 + rt * 16 + l15];

#pragma unroll
      for (int ki = 0; ki < 16; ki++) {
        const int cur = ki & 1, nxt = cur ^ 1;
        if (ki < 15) {
          const int k0n = (ki + 1) * 32;
#pragma unroll
          for (int g = 0; g < 4; g++)
            bv[nxt][g] = w1q[((g * 16 + nbb) * 64 + (ki + 1) * 4 + quad) * 16 + l15];
          const u32x4* ab = (k0n < 256)
              ? (lh1 + wr * 2048 + ((k0n >> 3) + quad) * 64)
              : (lh2 + rd * 2048 + (((k0n - 256) >> 3) + quad) * 64);
#pragma unroll
          for (int rt = 0; rt < 4; rt++) av[nxt][rt] = ab[rt * 16 + l15];
        }
#pragma unroll
        for (int g = 0; g < 4; g++)
#pragma unroll
          for (int rt = 0; rt < 4; rt++)
            acc[g][rt] = mfma_bf16(av[cur][rt], bv[cur][g], acc[g][rt]);
      }
#pragma unroll
      for (int rt = 0; rt < 4; rt++)
#pragma unroll
        for (int r = 0; r < 4; r++) {
          float iv = sigm(acc[0][rt][r] + bs1[jt][0]);
          float fv = sigm(acc[1][rt][r] + bs1[jt][1]);
          float gv = tanh_fast(acc[2][rt][r] + bs1[jt][2]);
          float ov = sigm(acc[3][rt][r] + bs1[jt][3]);
          float cn = fv * c2[jt][rt][r] + iv * gv;
          c2[jt][rt][r] = cn;
          int row = rt * 16 + quad * 4 + r;
          int col = wave * 32 + jt * 16 + l15;
          lh2s[wr * 16384 + ((col >> 3) * 64 + row) * 8 + (col & 7)] =
              f2bf(ov * tanh_fast(cn));
        }
    }
    __syncthreads();  // B3: h2[wr] complete

    // ---- FC partial: logit += W_fc[t*256 + j] * h2_new[row][j] ----
    {
      int row = tid >> 3;
      int jq = (tid & 7) * 32;
      float s = 0.f;
#pragma unroll
      for (int kb = 0; kb < 4; kb++) {
        u32x4 hv = lh2[wr * 2048 + ((jq >> 3) + kb) * 64 + row];
        const f32x4 wA = *(const f32x4*)(Wfc + t * 256 + jq + kb * 8);
        const f32x4 wB = *(const f32x4*)(Wfc + t * 256 + jq + kb * 8 + 4);
#pragma unroll
        for (int e = 0; e < 2; e++) {
          unsigned u = hv[e];
          s += bf2f((unsigned short)(u & 0xffffu)) * wA[2 * e];
          s += bf2f((unsigned short)(u >> 16)) * wA[2 * e + 1];
        }
#pragma unroll
        for (int e = 0; e < 2; e++) {
          unsigned u = hv[2 + e];
          s += bf2f((unsigned short)(u & 0xffffu)) * wB[2 * e];
          s += bf2f((unsigned short)(u >> 16)) * wB[2 * e + 1];
        }
      }
      fc_acc += s;
    }
    // no barrier: next staging touches lds_x only (last read before B2);
    // dbuf guarantees no h region is rewritten while readable.
  }

  lds_red[tid] = fc_acc;  // [row(64)][slot(8)]
  __syncthreads();
  if (tid < 64) {
    float s = 0.f;
#pragma unroll
    for (int e = 0; e < 8; e++) s += lds_red[tid * 8 + e];
    out[rowg0 + tid] = sigm(s + bfc[0]);
  }
}

extern "C" void kernel_launch(void* const* d_in, const int* in_sizes, int n_in,
                              void* d_out, int out_size, void* d_ws, size_t ws_size,
                              hipStream_t stream) {
  const float* x    = (const float*)d_in[0];
  const float* Wih0 = (const float*)d_in[1];
  const float* Whh0 = (const float*)d_in[2];
  const float* bih0 = (const float*)d_in[3];
  const float* bhh0 = (const float*)d_in[4];
  const float* Wih1 = (const float*)d_in[5];
  const float* Whh1 = (const float*)d_in[6];
  const float* bih1 = (const float*)d_in[7];
  const float* bhh1 = (const float*)d_in[8];
  const float* Wfc  = (const float*)d_in[9];
  const float* bfc  = (const float*)d_in[10];
  float* out = (float*)d_out;

  unsigned short* W0p = (unsigned short*)d_ws;         // 1024*416 bf16
  unsigned short* W1p = W0p + 1024 * 416;              // 1024*512 bf16
  float* b0 = (float*)(W1p + 1024 * 512);              // 1024 f32
  float* b1 = b0 + 1024;                               // 1024 f32

  const int total = 1024 * 416 + 1024 * 512 + 2048;
  pack_weights<<<(total + 255) / 256, 256, 0, stream>>>(
      Wih0, Whh0, bih0, bhh0, Wih1, Whh1, bih1, bhh1, W0p, W1p, b0, b1);
  lstm_fused<<<256, NTHREADS, 0, stream>>>(x, W0p, W1p, b0, b1, Wfc, bfc, out);
}

// Round 5
// 1559.914 us; speedup vs baseline: 1.1385x; 1.1335x over previous
//
#include <hip/hip_runtime.h>

#define NTHREADS 512

typedef __attribute__((ext_vector_type(8))) short s16x8;
typedef __attribute__((ext_vector_type(4))) float f32x4;
typedef __attribute__((ext_vector_type(4))) unsigned int u32x4;

__device__ __forceinline__ unsigned short f2bf(float f) {
  unsigned u = __float_as_uint(f);
  u += 0x7fffu + ((u >> 16) & 1u);
  return (unsigned short)(u >> 16);
}
__device__ __forceinline__ float bf2f(unsigned short s) {
  return __uint_as_float(((unsigned)s) << 16);
}
__device__ __forceinline__ float sigm(float x) {
  return __builtin_amdgcn_rcpf(1.0f + __expf(-x));
}
__device__ __forceinline__ float tanh_fast(float x) {
  return 1.0f - 2.0f * __builtin_amdgcn_rcpf(1.0f + __expf(2.0f * x));
}
__device__ __forceinline__ f32x4 mfma_bf16(u32x4 a, u32x4 b, f32x4 c) {
  union { u32x4 u; s16x8 s; } ua, ub;
  ua.u = a; ub.u = b;
  return __builtin_amdgcn_mfma_f32_16x16x32_bf16(ua.s, ub.s, c, 0, 0, 0);
}

// AGPR pinning: rounds 1-4 showed the RA splits the gfx950 unified file
// 128 arch + 128 acc and never rebalances -> arch side spilled ~0.5 GB to
// scratch while ~64 AGPRs sat idle. Park the persistent c-state in the
// AGPR half explicitly.
__device__ __forceinline__ float agpr_st(float v) {
  float r;
  asm("v_accvgpr_write_b32 %0, %1" : "=a"(r) : "v"(v));
  return r;
}
__device__ __forceinline__ float agpr_ld(float a) {
  float r;
  asm("v_accvgpr_read_b32 %0, %1" : "=v"(r) : "a"(a));
  return r;
}

// ---------------- weight pre-pack (unchanged, verified) ----------------
// W0p: layer0 combined [n=4H][K=416] (k<160: W_ih0, else W_hh0), bf16,
//      layout [nblk][kblk][16 n][8 k]; W1p: layer1 K=512, KB=64.
// b0/b1: b_ih + b_hh pre-summed, f32.
__global__ void pack_weights(const float* __restrict__ Wih0, const float* __restrict__ Whh0,
                             const float* __restrict__ bih0, const float* __restrict__ bhh0,
                             const float* __restrict__ Wih1, const float* __restrict__ Whh1,
                             const float* __restrict__ bih1, const float* __restrict__ bhh1,
                             unsigned short* __restrict__ W0p, unsigned short* __restrict__ W1p,
                             float* __restrict__ b0, float* __restrict__ b1) {
  int e = blockIdx.x * 256 + threadIdx.x;
  const int N0 = 1024 * 416;
  const int N1 = 1024 * 512;
  if (e < N0) {
    int kk = e & 7, t1 = e >> 3;
    int n = t1 & 15, t2 = t1 >> 4;
    int kb = t2 % 52, nb = t2 / 52;
    int gn = nb * 16 + n, k = kb * 8 + kk;
    float v = (k < 160) ? Wih0[gn * 160 + k] : Whh0[gn * 256 + (k - 160)];
    W0p[e] = f2bf(v);
  } else if (e < N0 + N1) {
    int e2 = e - N0;
    int kk = e2 & 7, t1 = e2 >> 3;
    int n = t1 & 15, t2 = t1 >> 4;
    int kb = t2 & 63, nb = t2 >> 6;
    int gn = nb * 16 + n, k = kb * 8 + kk;
    float v = (k < 256) ? Wih1[gn * 256 + k] : Whh1[gn * 256 + (k - 256)];
    W1p[e2] = f2bf(v);
  } else if (e < N0 + N1 + 1024) {
    int n = e - (N0 + N1);
    b0[n] = bih0[n] + bhh0[n];
  } else if (e < N0 + N1 + 2048) {
    int n = e - (N0 + N1 + 1024);
    b1[n] = bih1[n] + bhh1[n];
  }
}

// ---------------- fused 2-layer LSTM + FC ----------------
// 256 blocks x 512 threads; block owns 64 batch rows for all 10 steps.
// LDS 158 KB (1 blk/CU, 2 waves/SIMD): x-tile + DOUBLE-BUFFERED h1/h2 in
// bf16 A-layout [kblk][row][8k] + biases; 3 barriers/step.
// Register plan (observed split: 128 arch + 128 acc per wave):
//   AGPR: MFMA acc 64 + c-state 64 (pinned via v_accvgpr) = 128
//   arch: av dbuf 32 + bv dbuf 32 + addr/temps ~30        = ~95 <= 128
__global__ __attribute__((amdgpu_flat_work_group_size(NTHREADS, NTHREADS),
                          amdgpu_waves_per_eu(2, 2)))
void lstm_fused(const float* __restrict__ x,
                const unsigned short* __restrict__ W0p,
                const unsigned short* __restrict__ W1p,
                const float* __restrict__ b0,
                const float* __restrict__ b1,
                const float* __restrict__ Wfc,
                const float* __restrict__ bfc,
                float* __restrict__ out) {
  __shared__ unsigned int lds_x[20 * 64 * 4];   // 20480 B
  __shared__ unsigned int lds_h1[16384];        // 65536 B = 2 bufs x [32 kblk][64 row][8k]
  __shared__ unsigned int lds_h2[16384];        // 65536 B
  __shared__ float lds_red[512];                // 2048 B
  __shared__ float lds_b0[1024];                // 4096 B
  __shared__ float lds_b1[1024];                // 4096 B   total 161792 B

  const int tid = threadIdx.x;
  const int wave = tid >> 6;
  const int lane = tid & 63;
  const int l15 = lane & 15;
  const int quad = lane >> 4;
  const long rowg0 = (long)blockIdx.x * 64;

  for (int i = tid; i < 16384; i += NTHREADS) { lds_h1[i] = 0u; lds_h2[i] = 0u; }
  for (int i = tid; i < 1024; i += NTHREADS) { lds_b0[i] = b0[i]; lds_b1[i] = b1[i]; }

  // persistent c-state, pinned to AGPRs (64 values/lane across both layers)
  float c0a[2][4][4], c2a[2][4][4];
#pragma unroll
  for (int jt = 0; jt < 2; jt++)
#pragma unroll
    for (int rt = 0; rt < 4; rt++)
#pragma unroll
      for (int r = 0; r < 4; r++) {
        c0a[jt][rt][r] = agpr_st(0.f);
        c2a[jt][rt][r] = agpr_st(0.f);
      }
  float fc_acc = 0.0f;

  const u32x4* lxs = (const u32x4*)lds_x;
  const u32x4* lh1 = (const u32x4*)lds_h1;
  const u32x4* lh2 = (const u32x4*)lds_h2;
  unsigned short* lh1s = (unsigned short*)lds_h1;
  unsigned short* lh2s = (unsigned short*)lds_h2;
  const u32x4* w0q = (const u32x4*)W0p;
  const u32x4* w1q = (const u32x4*)W1p;

  for (int t = 0; t < 10; t++) {
    const int rd = t & 1;        // prev-h buffer
    const int wr = rd ^ 1;       // new-h buffer

    // ---- stage x_t -> lds_x (bf16 A-layout) ----
#pragma unroll
    for (int s = 0; s < 5; s++) {
      int p = tid + s * NTHREADS;          // 2560 f32x4 = 64 rows x 40 quads
      int row = p / 40;
      int kq = p - row * 40;
      const f32x4 v = __builtin_nontemporal_load(
          (const f32x4*)(x + (rowg0 + row) * 1600 + t * 160 + kq * 4));
      unsigned lo = (unsigned)f2bf(v[0]) | ((unsigned)f2bf(v[1]) << 16);
      unsigned hi = (unsigned)f2bf(v[2]) | ((unsigned)f2bf(v[3]) << 16);
      int base = (kq >> 1) * 256 + row * 4 + (kq & 1) * 2;
      lds_x[base] = lo;
      lds_x[base + 1] = hi;
    }
    __syncthreads();  // B1: x staged; h1[rd] stable from prev step

    // ======== layer 0: K=416 ([x_t | h1_prev]) ========
#pragma unroll
    for (int jt = 0; jt < 2; jt++) {
      const int nbb = wave * 2 + jt;
      f32x4 acc[4][4];
#pragma unroll
      for (int g = 0; g < 4; g++)
#pragma unroll
        for (int rt = 0; rt < 4; rt++) acc[g][rt] = (f32x4){0.f, 0.f, 0.f, 0.f};

      u32x4 av[2][4], bv[2][4];
#pragma unroll
      for (int g = 0; g < 4; g++)
        bv[0][g] = w0q[((g * 16 + nbb) * 52 + quad) * 16 + l15];
#pragma unroll
      for (int rt = 0; rt < 4; rt++) av[0][rt] = lxs[quad * 64 + rt * 16 + l15];

#pragma unroll
      for (int ki = 0; ki < 13; ki++) {
        const int cur = ki & 1, nxt = cur ^ 1;
        if (ki < 12) {
          const int k0n = (ki + 1) * 32;
#pragma unroll
          for (int g = 0; g < 4; g++)
            bv[nxt][g] = w0q[((g * 16 + nbb) * 52 + (ki + 1) * 4 + quad) * 16 + l15];
          const u32x4* ab = (k0n < 160)
              ? (lxs + ((k0n >> 3) + quad) * 64)
              : (lh1 + rd * 2048 + (((k0n - 160) >> 3) + quad) * 64);
#pragma unroll
          for (int rt = 0; rt < 4; rt++) av[nxt][rt] = ab[rt * 16 + l15];
        }
#pragma unroll
        for (int g = 0; g < 4; g++)
#pragma unroll
          for (int rt = 0; rt < 4; rt++)
            acc[g][rt] = mfma_bf16(av[cur][rt], bv[cur][g], acc[g][rt]);
      }
      // epilogue: gates -> c0 (AGPR), h1 -> lds_h1[wr]
      float b_i = lds_b0[0 * 256 + wave * 32 + jt * 16 + l15];
      float b_f = lds_b0[1 * 256 + wave * 32 + jt * 16 + l15];
      float b_g = lds_b0[2 * 256 + wave * 32 + jt * 16 + l15];
      float b_o = lds_b0[3 * 256 + wave * 32 + jt * 16 + l15];
#pragma unroll
      for (int rt = 0; rt < 4; rt++)
#pragma unroll
        for (int r = 0; r < 4; r++) {
          float iv = sigm(acc[0][rt][r] + b_i);
          float fv = sigm(acc[1][rt][r] + b_f);
          float gv = tanh_fast(acc[2][rt][r] + b_g);
          float ov = sigm(acc[3][rt][r] + b_o);
          float cn = fv * agpr_ld(c0a[jt][rt][r]) + iv * gv;
          c0a[jt][rt][r] = agpr_st(cn);
          int row = rt * 16 + quad * 4 + r;
          int col = wave * 32 + jt * 16 + l15;
          lh1s[wr * 16384 + ((col >> 3) * 64 + row) * 8 + (col & 7)] =
              f2bf(ov * tanh_fast(cn));
        }
    }
    __syncthreads();  // B2: h1[wr] complete

    // ======== layer 1: K=512 ([h1_new | h2_prev]) ========
#pragma unroll
    for (int jt = 0; jt < 2; jt++) {
      const int nbb = wave * 2 + jt;
      f32x4 acc[4][4];
#pragma unroll
      for (int g = 0; g < 4; g++)
#pragma unroll
        for (int rt = 0; rt < 4; rt++) acc[g][rt] = (f32x4){0.f, 0.f, 0.f, 0.f};

      u32x4 av[2][4], bv[2][4];
#pragma unroll
      for (int g = 0; g < 4; g++)
        bv[0][g] = w1q[((g * 16 + nbb) * 64 + quad) * 16 + l15];
#pragma unroll
      for (int rt = 0; rt < 4; rt++)
        av[0][rt] = lh1[wr * 2048 + quad * 64 + rt * 16 + l15];

#pragma unroll
      for (int ki = 0; ki < 16; ki++) {
        const int cur = ki & 1, nxt = cur ^ 1;
        if (ki < 15) {
          const int k0n = (ki + 1) * 32;
#pragma unroll
          for (int g = 0; g < 4; g++)
            bv[nxt][g] = w1q[((g * 16 + nbb) * 64 + (ki + 1) * 4 + quad) * 16 + l15];
          const u32x4* ab = (k0n < 256)
              ? (lh1 + wr * 2048 + ((k0n >> 3) + quad) * 64)
              : (lh2 + rd * 2048 + (((k0n - 256) >> 3) + quad) * 64);
#pragma unroll
          for (int rt = 0; rt < 4; rt++) av[nxt][rt] = ab[rt * 16 + l15];
        }
#pragma unroll
        for (int g = 0; g < 4; g++)
#pragma unroll
          for (int rt = 0; rt < 4; rt++)
            acc[g][rt] = mfma_bf16(av[cur][rt], bv[cur][g], acc[g][rt]);
      }
      float b_i = lds_b1[0 * 256 + wave * 32 + jt * 16 + l15];
      float b_f = lds_b1[1 * 256 + wave * 32 + jt * 16 + l15];
      float b_g = lds_b1[2 * 256 + wave * 32 + jt * 16 + l15];
      float b_o = lds_b1[3 * 256 + wave * 32 + jt * 16 + l15];
#pragma unroll
      for (int rt = 0; rt < 4; rt++)
#pragma unroll
        for (int r = 0; r < 4; r++) {
          float iv = sigm(acc[0][rt][r] + b_i);
          float fv = sigm(acc[1][rt][r] + b_f);
          float gv = tanh_fast(acc[2][rt][r] + b_g);
          float ov = sigm(acc[3][rt][r] + b_o);
          float cn = fv * agpr_ld(c2a[jt][rt][r]) + iv * gv;
          c2a[jt][rt][r] = agpr_st(cn);
          int row = rt * 16 + quad * 4 + r;
          int col = wave * 32 + jt * 16 + l15;
          lh2s[wr * 16384 + ((col >> 3) * 64 + row) * 8 + (col & 7)] =
              f2bf(ov * tanh_fast(cn));
        }
    }
    __syncthreads();  // B3: h2[wr] complete

    // ---- FC partial: logit += W_fc[t*256 + j] * h2_new[row][j] ----
    {
      int row = tid >> 3;
      int jq = (tid & 7) * 32;
      float s = 0.f;
#pragma unroll
      for (int kb = 0; kb < 4; kb++) {
        u32x4 hv = lh2[wr * 2048 + ((jq >> 3) + kb) * 64 + row];
        const f32x4 wA = *(const f32x4*)(Wfc + t * 256 + jq + kb * 8);
        const f32x4 wB = *(const f32x4*)(Wfc + t * 256 + jq + kb * 8 + 4);
#pragma unroll
        for (int e = 0; e < 2; e++) {
          unsigned u = hv[e];
          s += bf2f((unsigned short)(u & 0xffffu)) * wA[2 * e];
          s += bf2f((unsigned short)(u >> 16)) * wA[2 * e + 1];
        }
#pragma unroll
        for (int e = 0; e < 2; e++) {
          unsigned u = hv[2 + e];
          s += bf2f((unsigned short)(u & 0xffffu)) * wB[2 * e];
          s += bf2f((unsigned short)(u >> 16)) * wB[2 * e + 1];
        }
      }
      fc_acc += s;
    }
    // no barrier: next staging touches lds_x only (last read before B2);
    // dbuf guarantees no h region is rewritten while readable.
  }

  lds_red[tid] = fc_acc;  // [row(64)][slot(8)]
  __syncthreads();
  if (tid < 64) {
    float s = 0.f;
#pragma unroll
    for (int e = 0; e < 8; e++) s += lds_red[tid * 8 + e];
    out[rowg0 + tid] = sigm(s + bfc[0]);
  }
}

extern "C" void kernel_launch(void* const* d_in, const int* in_sizes, int n_in,
                              void* d_out, int out_size, void* d_ws, size_t ws_size,
                              hipStream_t stream) {
  const float* x    = (const float*)d_in[0];
  const float* Wih0 = (const float*)d_in[1];
  const float* Whh0 = (const float*)d_in[2];
  const float* bih0 = (const float*)d_in[3];
  const float* bhh0 = (const float*)d_in[4];
  const float* Wih1 = (const float*)d_in[5];
  const float* Whh1 = (const float*)d_in[6];
  const float* bih1 = (const float*)d_in[7];
  const float* bhh1 = (const float*)d_in[8];
  const float* Wfc  = (const float*)d_in[9];
  const float* bfc  = (const float*)d_in[10];
  float* out = (float*)d_out;

  unsigned short* W0p = (unsigned short*)d_ws;         // 1024*416 bf16
  unsigned short* W1p = W0p + 1024 * 416;              // 1024*512 bf16
  float* b0 = (float*)(W1p + 1024 * 512);              // 1024 f32
  float* b1 = b0 + 1024;                               // 1024 f32

  const int total = 1024 * 416 + 1024 * 512 + 2048;
  pack_weights<<<(total + 255) / 256, 256, 0, stream>>>(
      Wih0, Whh0, bih0, bhh0, Wih1, Whh1, bih1, bhh1, W0p, W1p, b0, b1);
  lstm_fused<<<256, NTHREADS, 0, stream>>>(x, W0p, W1p, b0, b1, Wfc, bfc, out);
}

// Round 6
// 1500.420 us; speedup vs baseline: 1.1837x; 1.0397x over previous
//
#include <hip/hip_runtime.h>

#define NTHREADS 512

typedef __attribute__((ext_vector_type(8))) short s16x8;
typedef __attribute__((ext_vector_type(4))) float f32x4;
typedef __attribute__((ext_vector_type(4))) unsigned int u32x4;

__device__ __forceinline__ unsigned short f2bf(float f) {
  unsigned u = __float_as_uint(f);
  u += 0x7fffu + ((u >> 16) & 1u);
  return (unsigned short)(u >> 16);
}
__device__ __forceinline__ float bf2f(unsigned short s) {
  return __uint_as_float(((unsigned)s) << 16);
}
__device__ __forceinline__ float sigm(float x) {
  return __builtin_amdgcn_rcpf(1.0f + __expf(-x));
}
__device__ __forceinline__ float tanh_fast(float x) {
  return 1.0f - 2.0f * __builtin_amdgcn_rcpf(1.0f + __expf(2.0f * x));
}

// Register-file discipline (rounds 1-5 evidence): gfx950 unified file is
// split 128 arch + 128 acc per wave at this occupancy and the RA does not
// rebalance; anything the builtin MFMA keeps in arch VGPRs fights the
// staging registers and spills (~0.4-0.9 GB scratch writes observed).
// Fix: force BOTH the MFMA accumulators and the persistent c-state into
// the acc half with explicit "a"-class constraints.
__device__ __forceinline__ float agpr_st(float v) {
  float r;
  asm("v_accvgpr_write_b32 %0, %1" : "=a"(r) : "v"(v));
  return r;
}
__device__ __forceinline__ float agpr_ld(float a) {
  float r;
  asm("v_accvgpr_read_b32 %0, %1" : "=v"(r) : "a"(a));
  return r;
}
// D(acc) = A*B + D(acc), C/D pinned to AGPRs
__device__ __forceinline__ void mfma_bf16_acc(u32x4 a, u32x4 b, f32x4& c) {
  union { u32x4 u; s16x8 s; } ua, ub;
  ua.u = a; ub.u = b;
  asm("v_mfma_f32_16x16x32_bf16 %0, %1, %2, %0"
      : "+a"(c)
      : "v"(ua.s), "v"(ub.s));
}

// ---------------- weight pre-pack (unchanged, verified) ----------------
// W0p: layer0 combined [n=4H][K=416] (k<160: W_ih0, else W_hh0), bf16,
//      layout [nblk][kblk][16 n][8 k]; W1p: layer1 K=512, KB=64.
// b0/b1: b_ih + b_hh pre-summed, f32.
__global__ void pack_weights(const float* __restrict__ Wih0, const float* __restrict__ Whh0,
                             const float* __restrict__ bih0, const float* __restrict__ bhh0,
                             const float* __restrict__ Wih1, const float* __restrict__ Whh1,
                             const float* __restrict__ bih1, const float* __restrict__ bhh1,
                             unsigned short* __restrict__ W0p, unsigned short* __restrict__ W1p,
                             float* __restrict__ b0, float* __restrict__ b1) {
  int e = blockIdx.x * 256 + threadIdx.x;
  const int N0 = 1024 * 416;
  const int N1 = 1024 * 512;
  if (e < N0) {
    int kk = e & 7, t1 = e >> 3;
    int n = t1 & 15, t2 = t1 >> 4;
    int kb = t2 % 52, nb = t2 / 52;
    int gn = nb * 16 + n, k = kb * 8 + kk;
    float v = (k < 160) ? Wih0[gn * 160 + k] : Whh0[gn * 256 + (k - 160)];
    W0p[e] = f2bf(v);
  } else if (e < N0 + N1) {
    int e2 = e - N0;
    int kk = e2 & 7, t1 = e2 >> 3;
    int n = t1 & 15, t2 = t1 >> 4;
    int kb = t2 & 63, nb = t2 >> 6;
    int gn = nb * 16 + n, k = kb * 8 + kk;
    float v = (k < 256) ? Wih1[gn * 256 + k] : Whh1[gn * 256 + (k - 256)];
    W1p[e2] = f2bf(v);
  } else if (e < N0 + N1 + 1024) {
    int n = e - (N0 + N1);
    b0[n] = bih0[n] + bhh0[n];
  } else if (e < N0 + N1 + 2048) {
    int n = e - (N0 + N1 + 1024);
    b1[n] = bih1[n] + bhh1[n];
  }
}

// ---------------- fused 2-layer LSTM + FC ----------------
// 256 blocks x 512 threads; block owns 64 batch rows for all 10 steps.
// LDS 158 KB (1 blk/CU, 2 waves/SIMD): x-tile + DOUBLE-BUFFERED h1/h2 in
// bf16 A-layout [kblk][row][8k] + biases; 3 barriers/step.
// Register plan (128 arch + 128 acc split):
//   AGPR: MFMA acc 64 (asm "+a") + c-state 64 (agpr_st/ld) = 128
//   arch: av dbuf 32 + bv dbuf 32 + addr/temps ~30         = ~95 <= 128
__global__ __attribute__((amdgpu_flat_work_group_size(NTHREADS, NTHREADS),
                          amdgpu_waves_per_eu(2, 2)))
void lstm_fused(const float* __restrict__ x,
                const unsigned short* __restrict__ W0p,
                const unsigned short* __restrict__ W1p,
                const float* __restrict__ b0,
                const float* __restrict__ b1,
                const float* __restrict__ Wfc,
                const float* __restrict__ bfc,
                float* __restrict__ out) {
  __shared__ unsigned int lds_x[20 * 64 * 4];   // 20480 B
  __shared__ unsigned int lds_h1[16384];        // 65536 B = 2 bufs x [32 kblk][64 row][8k]
  __shared__ unsigned int lds_h2[16384];        // 65536 B
  __shared__ float lds_red[512];                // 2048 B
  __shared__ float lds_b0[1024];                // 4096 B
  __shared__ float lds_b1[1024];                // 4096 B   total 161792 B

  const int tid = threadIdx.x;
  const int wave = tid >> 6;
  const int lane = tid & 63;
  const int l15 = lane & 15;
  const int quad = lane >> 4;
  const long rowg0 = (long)blockIdx.x * 64;

  for (int i = tid; i < 16384; i += NTHREADS) { lds_h1[i] = 0u; lds_h2[i] = 0u; }
  for (int i = tid; i < 1024; i += NTHREADS) { lds_b0[i] = b0[i]; lds_b1[i] = b1[i]; }

  // persistent c-state, pinned to AGPRs (64 values/lane across both layers)
  float c0a[2][4][4], c2a[2][4][4];
#pragma unroll
  for (int jt = 0; jt < 2; jt++)
#pragma unroll
    for (int rt = 0; rt < 4; rt++)
#pragma unroll
      for (int r = 0; r < 4; r++) {
        c0a[jt][rt][r] = agpr_st(0.f);
        c2a[jt][rt][r] = agpr_st(0.f);
      }
  float fc_acc = 0.0f;

  const u32x4* lxs = (const u32x4*)lds_x;
  const u32x4* lh1 = (const u32x4*)lds_h1;
  const u32x4* lh2 = (const u32x4*)lds_h2;
  unsigned short* lh1s = (unsigned short*)lds_h1;
  unsigned short* lh2s = (unsigned short*)lds_h2;
  const u32x4* w0q = (const u32x4*)W0p;
  const u32x4* w1q = (const u32x4*)W1p;

  for (int t = 0; t < 10; t++) {
    const int rd = t & 1;        // prev-h buffer
    const int wr = rd ^ 1;       // new-h buffer

    // ---- stage x_t -> lds_x (bf16 A-layout) ----
#pragma unroll
    for (int s = 0; s < 5; s++) {
      int p = tid + s * NTHREADS;          // 2560 f32x4 = 64 rows x 40 quads
      int row = p / 40;
      int kq = p - row * 40;
      const f32x4 v = __builtin_nontemporal_load(
          (const f32x4*)(x + (rowg0 + row) * 1600 + t * 160 + kq * 4));
      unsigned lo = (unsigned)f2bf(v[0]) | ((unsigned)f2bf(v[1]) << 16);
      unsigned hi = (unsigned)f2bf(v[2]) | ((unsigned)f2bf(v[3]) << 16);
      int base = (kq >> 1) * 256 + row * 4 + (kq & 1) * 2;
      lds_x[base] = lo;
      lds_x[base + 1] = hi;
    }
    __syncthreads();  // B1: x staged; h1[rd] stable from prev step

    // ======== layer 0: K=416 ([x_t | h1_prev]) ========
#pragma unroll
    for (int jt = 0; jt < 2; jt++) {
      const int nbb = wave * 2 + jt;
      f32x4 acc[4][4];
#pragma unroll
      for (int g = 0; g < 4; g++)
#pragma unroll
        for (int rt = 0; rt < 4; rt++) acc[g][rt] = (f32x4){0.f, 0.f, 0.f, 0.f};

      u32x4 av[2][4], bv[2][4];
#pragma unroll
      for (int g = 0; g < 4; g++)
        bv[0][g] = w0q[((g * 16 + nbb) * 52 + quad) * 16 + l15];
#pragma unroll
      for (int rt = 0; rt < 4; rt++) av[0][rt] = lxs[quad * 64 + rt * 16 + l15];

#pragma unroll
      for (int ki = 0; ki < 13; ki++) {
        const int cur = ki & 1, nxt = cur ^ 1;
        if (ki < 12) {
          const int k0n = (ki + 1) * 32;
#pragma unroll
          for (int g = 0; g < 4; g++)
            bv[nxt][g] = w0q[((g * 16 + nbb) * 52 + (ki + 1) * 4 + quad) * 16 + l15];
          const u32x4* ab = (k0n < 160)
              ? (lxs + ((k0n >> 3) + quad) * 64)
              : (lh1 + rd * 2048 + (((k0n - 160) >> 3) + quad) * 64);
#pragma unroll
          for (int rt = 0; rt < 4; rt++) av[nxt][rt] = ab[rt * 16 + l15];
        }
#pragma unroll
        for (int g = 0; g < 4; g++)
#pragma unroll
          for (int rt = 0; rt < 4; rt++)
            mfma_bf16_acc(av[cur][rt], bv[cur][g], acc[g][rt]);
      }
      // epilogue: gates -> c0 (AGPR), h1 -> lds_h1[wr]
      float b_i = lds_b0[0 * 256 + wave * 32 + jt * 16 + l15];
      float b_f = lds_b0[1 * 256 + wave * 32 + jt * 16 + l15];
      float b_g = lds_b0[2 * 256 + wave * 32 + jt * 16 + l15];
      float b_o = lds_b0[3 * 256 + wave * 32 + jt * 16 + l15];
#pragma unroll
      for (int rt = 0; rt < 4; rt++)
#pragma unroll
        for (int r = 0; r < 4; r++) {
          float iv = sigm(acc[0][rt][r] + b_i);
          float fv = sigm(acc[1][rt][r] + b_f);
          float gv = tanh_fast(acc[2][rt][r] + b_g);
          float ov = sigm(acc[3][rt][r] + b_o);
          float cn = fv * agpr_ld(c0a[jt][rt][r]) + iv * gv;
          c0a[jt][rt][r] = agpr_st(cn);
          int row = rt * 16 + quad * 4 + r;
          int col = wave * 32 + jt * 16 + l15;
          lh1s[wr * 16384 + ((col >> 3) * 64 + row) * 8 + (col & 7)] =
              f2bf(ov * tanh_fast(cn));
        }
    }
    __syncthreads();  // B2: h1[wr] complete

    // ======== layer 1: K=512 ([h1_new | h2_prev]) ========
#pragma unroll
    for (int jt = 0; jt < 2; jt++) {
      const int nbb = wave * 2 + jt;
      f32x4 acc[4][4];
#pragma unroll
      for (int g = 0; g < 4; g++)
#pragma unroll
        for (int rt = 0; rt < 4; rt++) acc[g][rt] = (f32x4){0.f, 0.f, 0.f, 0.f};

      u32x4 av[2][4], bv[2][4];
#pragma unroll
      for (int g = 0; g < 4; g++)
        bv[0][g] = w1q[((g * 16 + nbb) * 64 + quad) * 16 + l15];
#pragma unroll
      for (int rt = 0; rt < 4; rt++)
        av[0][rt] = lh1[wr * 2048 + quad * 64 + rt * 16 + l15];

#pragma unroll
      for (int ki = 0; ki < 16; ki++) {
        const int cur = ki & 1, nxt = cur ^ 1;
        if (ki < 15) {
          const int k0n = (ki + 1) * 32;
#pragma unroll
          for (int g = 0; g < 4; g++)
            bv[nxt][g] = w1q[((g * 16 + nbb) * 64 + (ki + 1) * 4 + quad) * 16 + l15];
          const u32x4* ab = (k0n < 256)
              ? (lh1 + wr * 2048 + ((k0n >> 3) + quad) * 64)
              : (lh2 + rd * 2048 + (((k0n - 256) >> 3) + quad) * 64);
#pragma unroll
          for (int rt = 0; rt < 4; rt++) av[nxt][rt] = ab[rt * 16 + l15];
        }
#pragma unroll
        for (int g = 0; g < 4; g++)
#pragma unroll
          for (int rt = 0; rt < 4; rt++)
            mfma_bf16_acc(av[cur][rt], bv[cur][g], acc[g][rt]);
      }
      float b_i = lds_b1[0 * 256 + wave * 32 + jt * 16 + l15];
      float b_f = lds_b1[1 * 256 + wave * 32 + jt * 16 + l15];
      float b_g = lds_b1[2 * 256 + wave * 32 + jt * 16 + l15];
      float b_o = lds_b1[3 * 256 + wave * 32 + jt * 16 + l15];
#pragma unroll
      for (int rt = 0; rt < 4; rt++)
#pragma unroll
        for (int r = 0; r < 4; r++) {
          float iv = sigm(acc[0][rt][r] + b_i);
          float fv = sigm(acc[1][rt][r] + b_f);
          float gv = tanh_fast(acc[2][rt][r] + b_g);
          float ov = sigm(acc[3][rt][r] + b_o);
          float cn = fv * agpr_ld(c2a[jt][rt][r]) + iv * gv;
          c2a[jt][rt][r] = agpr_st(cn);
          int row = rt * 16 + quad * 4 + r;
          int col = wave * 32 + jt * 16 + l15;
          lh2s[wr * 16384 + ((col >> 3) * 64 + row) * 8 + (col & 7)] =
              f2bf(ov * tanh_fast(cn));
        }
    }
    __syncthreads();  // B3: h2[wr] complete

    // ---- FC partial: logit += W_fc[t*256 + j] * h2_new[row][j] ----
    {
      int row = tid >> 3;
      int jq = (tid & 7) * 32;
      float s = 0.f;
#pragma unroll
      for (int kb = 0; kb < 4; kb++) {
        u32x4 hv = lh2[wr * 2048 + ((jq >> 3) + kb) * 64 + row];
        const f32x4 wA = *(const f32x4*)(Wfc + t * 256 + jq + kb * 8);
        const f32x4 wB = *(const f32x4*)(Wfc + t * 256 + jq + kb * 8 + 4);
#pragma unroll
        for (int e = 0; e < 2; e++) {
          unsigned u = hv[e];
          s += bf2f((unsigned short)(u & 0xffffu)) * wA[2 * e];
          s += bf2f((unsigned short)(u >> 16)) * wA[2 * e + 1];
        }
#pragma unroll
        for (int e = 0; e < 2; e++) {
          unsigned u = hv[2 + e];
          s += bf2f((unsigned short)(u & 0xffffu)) * wB[2 * e];
          s += bf2f((unsigned short)(u >> 16)) * wB[2 * e + 1];
        }
      }
      fc_acc += s;
    }
    // no barrier: next staging touches lds_x only (last read before B2);
    // dbuf guarantees no h region is rewritten while readable.
  }

  lds_red[tid] = fc_acc;  // [row(64)][slot(8)]
  __syncthreads();
  if (tid < 64) {
    float s = 0.f;
#pragma unroll
    for (int e = 0; e < 8; e++) s += lds_red[tid * 8 + e];
    out[rowg0 + tid] = sigm(s + bfc[0]);
  }
}

extern "C" void kernel_launch(void* const* d_in, const int* in_sizes, int n_in,
                              void* d_out, int out_size, void* d_ws, size_t ws_size,
                              hipStream_t stream) {
  const float* x    = (const float*)d_in[0];
  const float* Wih0 = (const float*)d_in[1];
  const float* Whh0 = (const float*)d_in[2];
  const float* bih0 = (const float*)d_in[3];
  const float* bhh0 = (const float*)d_in[4];
  const float* Wih1 = (const float*)d_in[5];
  const float* Whh1 = (const float*)d_in[6];
  const float* bih1 = (const float*)d_in[7];
  const float* bhh1 = (const float*)d_in[8];
  const float* Wfc  = (const float*)d_in[9];
  const float* bfc  = (const float*)d_in[10];
  float* out = (float*)d_out;

  unsigned short* W0p = (unsigned short*)d_ws;         // 1024*416 bf16
  unsigned short* W1p = W0p + 1024 * 416;              // 1024*512 bf16
  float* b0 = (float*)(W1p + 1024 * 512);              // 1024 f32
  float* b1 = b0 + 1024;                               // 1024 f32

  const int total = 1024 * 416 + 1024 * 512 + 2048;
  pack_weights<<<(total + 255) / 256, 256, 0, stream>>>(
      Wih0, Whh0, bih0, bhh0, Wih1, Whh1, bih1, bhh1, W0p, W1p, b0, b1);
  lstm_fused<<<256, NTHREADS, 0, stream>>>(x, W0p, W1p, b0, b1, Wfc, bfc, out);
}